// Round 9
// baseline (653.610 us; speedup 1.0000x reference)
//
#include <hip/hip_runtime.h>

// VQ argmin: exact bit-level emulation of numpy fp32 reference:
//   A  = np.sum(flat*flat, axis=1)     (numpy pairwise-sum tree, fp32)
//   M2 = (2*flat) @ emb.T              (BLAS: sequential fp32 fma chain over d)
//   dist = (A - M2) + ee;  argmin_k (first-min ties)
// z_e_x: [B=16, D=256, H=64, W=64] fp32; embedding: [K=1024, D=256] fp32
// out: int32 [65536]
//
// R12: er off the scalar path. R3/R11's 31-34% stall is the s_load er
// stream (256 B/row, ~200cy L2, K$ 16KB << 64KB stream, SGPR file too
// small to prefetch a row ahead -- R4/R5/R8 closed every scalar-side fix).
// Change ONE thing vs R11: er now staged into LDS via async
// global_load_lds (T3 2-phase: issue chunk ch+1 -> compute ch -> barrier)
// and read as uniform-address ds_read_b128 BROADCASTS (conflict-free,
// ~120cy, deep lgkmcnt pipelining). R3 skeleton untouched: 1 n/thread,
// acc[64], z VGPR ping-pong, KT=64/NKT=4/NSPLIT=4, (256,4), grid 1024.
// Unlike the failed R9/R10 GEMMs: no micro-tile restructure, z path
// identical, 16 barriers total each preceded by ~8K cycles of compute.
// LDS 2x16KB chunks (64 d x 64 k), 4 blocks x 32KB = 128KB/CU (<160).
// Exact: cbuf is a bit-copy of eT; fmaf chain d-ascending unchanged;
// epilogue/u64 (distbits,k) atomicMin ties unchanged (verified 5x).

#define D_DIM  256
#define K_DIM  1024
#define HW     4096
#define N_TOT  65536
#define NSPLIT 4
#define NKT    4
#define KT     64                 // acc regs per thread = k's per kt tile
#define KSPL   (K_DIM / NSPLIT)   // 256 k's per split = NKT*KT
#define DCH    64                 // d's per LDS chunk
#define F32MAX 3.402823466e38f

// ---- numpy pairwise_sum for ||e_k||^2 (n=256 = two 128-blocks of 8 accs)

__global__ void ee_kernel(const float* __restrict__ e, float* __restrict__ ee) {
#pragma clang fp contract(off)
    int k = blockIdx.x * blockDim.x + threadIdx.x;
    if (k >= K_DIM) return;
    const float* row = e + (size_t)k * D_DIM;
    float total = 0.0f;
    #pragma unroll
    for (int h = 0; h < 2; ++h) {
        const float* a = row + h * 128;
        float r[8];
        #pragma unroll
        for (int j = 0; j < 8; ++j) { float v = a[j]; r[j] = v * v; }
        #pragma unroll
        for (int i = 8; i < 128; i += 8) {
            #pragma unroll
            for (int j = 0; j < 8; ++j) { float v = a[i + j]; r[j] = r[j] + v * v; }
        }
        float s = ((r[0] + r[1]) + (r[2] + r[3])) + ((r[4] + r[5]) + (r[6] + r[7]));
        total = (h == 0) ? s : (total + s);
    }
    ee[k] = total;
}

// ---- A = numpy pairwise ||z_n||^2: 2 threads per n, one 128-half each
// (halves are independent 8-acc chains; total = s0 + s1). Bitwise-exact.

__global__ void a_kernel(const float* __restrict__ z, float* __restrict__ A) {
#pragma clang fp contract(off)
    int t = blockIdx.x * blockDim.x + threadIdx.x;   // 0 .. 2*N_TOT-1
    int n = t >> 1;
    int h = t & 1;
    int b  = n >> 12;
    int hw = n & (HW - 1);
    const float* base = z + (size_t)b * D_DIM * HW + hw + (size_t)(h * 128) * HW;
    float r[8];
    #pragma unroll
    for (int j = 0; j < 8; ++j) { float v = base[(size_t)j * HW]; r[j] = v * v; }
    #pragma unroll
    for (int i = 8; i < 128; i += 8) {
        #pragma unroll
        for (int j = 0; j < 8; ++j) {
            float v = base[(size_t)(i + j) * HW];
            r[j] = r[j] + v * v;
        }
    }
    float s = ((r[0] + r[1]) + (r[2] + r[3])) + ((r[4] + r[5]) + (r[6] + r[7]));
    float other = __shfl_xor(s, 1);
    if (h == 0) A[n] = s + other;    // total = s_half0 + s_half1 (exact order)
}

// ---- transpose + fold the exact x2: eT[d][k] = 2*emb[k][d]

__global__ void et_kernel(const float* __restrict__ e, float* __restrict__ eT) {
    __shared__ float t[32][33];
    const int k0 = blockIdx.x * 32;
    const int d0 = blockIdx.y * 32;
    const int tx = threadIdx.x;         // 0..31
    const int ty = threadIdx.y;         // 0..7
    #pragma unroll
    for (int i = 0; i < 32; i += 8)
        t[ty + i][tx] = 2.0f * e[(size_t)(k0 + ty + i) * D_DIM + d0 + tx];
    __syncthreads();
    #pragma unroll
    for (int i = 0; i < 32; i += 8)
        eT[(size_t)(d0 + ty + i) * K_DIM + k0 + tx] = t[tx][ty + i];
}

// ---- async-stage one 64d x 64k eT chunk into LDS.
// Per op o: lane-linear 4KB slice; global src per-lane, LDS dest =
// wave-uniform base + lane*16B (hardware rule). fidx = o*1024 + 4t
// -> row = o*16 + (t>>4), col = 4*(t&15); 16-lane groups read 256B
// contiguous from one eT row (coalesced).

__device__ __forceinline__ void stage_issue(const float* __restrict__ eT,
                                            float* cb, int kbase, int d0, int t) {
    #pragma unroll
    for (int o = 0; o < 4; ++o) {
        const float* g = eT + (size_t)(d0 + o * 16 + (t >> 4)) * K_DIM
                       + kbase + (t & 15) * 4;
        float* l = cb + o * 1024 + (t >> 6) * 256;   // wave-uniform base
        __builtin_amdgcn_global_load_lds(
            (const __attribute__((address_space(1))) void*)g,
            (__attribute__((address_space(3))) void*)l, 16, 0, 0);
    }
}

// ---- z prefetch (8 d's, mod-256 wrap re-primes next kt automatically)

__device__ __forceinline__ void zpf(const float* __restrict__ zp, int df,
                                    float (&dst)[8]) {
    #pragma unroll
    for (int i = 0; i < 8; ++i)
        dst[i] = zp[(size_t)((df + i) & (D_DIM - 1)) * HW];
}

// ---- 8 d-rows of FMA from LDS broadcast. Uniform-address ds_read_b128
// (4 er floats/read, broadcast, conflict-free); q-groups keep only 4
// float4 transient to protect the 128-reg budget.

__device__ __forceinline__ void fma8(const float* cb, int rb,
                                     const float (&zr)[8], float (&acc)[KT]) {
#pragma clang fp contract(off)
    #pragma unroll
    for (int dd = 0; dd < 8; ++dd) {
        const float zv = zr[dd];
        const float4* er = (const float4*)(cb + (size_t)(rb + dd) * KT);
        #pragma unroll
        for (int q = 0; q < 4; ++q) {
            float4 e0 = er[q * 4 + 0];
            float4 e1 = er[q * 4 + 1];
            float4 e2 = er[q * 4 + 2];
            float4 e3 = er[q * 4 + 3];
            float* a = &acc[q * 16];
            a[0]  = fmaf(zv, e0.x, a[0]);  a[1]  = fmaf(zv, e0.y, a[1]);
            a[2]  = fmaf(zv, e0.z, a[2]);  a[3]  = fmaf(zv, e0.w, a[3]);
            a[4]  = fmaf(zv, e1.x, a[4]);  a[5]  = fmaf(zv, e1.y, a[5]);
            a[6]  = fmaf(zv, e1.z, a[6]);  a[7]  = fmaf(zv, e1.w, a[7]);
            a[8]  = fmaf(zv, e2.x, a[8]);  a[9]  = fmaf(zv, e2.y, a[9]);
            a[10] = fmaf(zv, e2.z, a[10]); a[11] = fmaf(zv, e2.w, a[11]);
            a[12] = fmaf(zv, e3.x, a[12]); a[13] = fmaf(zv, e3.y, a[13]);
            a[14] = fmaf(zv, e3.z, a[14]); a[15] = fmaf(zv, e3.w, a[15]);
        }
    }
}

// ---- main: 1 n per thread, er via LDS broadcast, 64-k acc tile.
// 4 blocks/CU, 4 waves/SIMD, 128-reg budget, 32 KB LDS/block.

__launch_bounds__(256, 4)
__global__ void vq_partial(const float* __restrict__ z, const float* __restrict__ eT,
                           const float* __restrict__ A, const float* __restrict__ ee,
                           unsigned long long* __restrict__ packed) {
#pragma clang fp contract(off)
    __shared__ __align__(16) float cbuf[2][DCH * KT];   // 2 x 16 KB

    const int t    = threadIdx.x;
    const int s    = blockIdx.x & (NSPLIT - 1);
    const int slab = blockIdx.x >> 2;
    const int n    = slab * 256 + t;
    const int b    = n >> 12;
    const int hw   = n & (HW - 1);
    const float* __restrict__ zp = z + (size_t)b * D_DIM * HW + hw;
    const int kb0 = s * KSPL;

    // prologue: issue stage 0, prime z, drain (vmcnt(0) at the barrier)
    stage_issue(eT, cbuf[0], kb0, 0, t);
    float za[8], zb[8];
    zpf(zp, 0, za);
    const float An = A[n];
    __syncthreads();

    float bestv = F32MAX;
    int   bestk = 0;

    #pragma unroll 1
    for (int kt = 0; kt < NKT; ++kt) {
        const int kbase = kb0 + kt * KT;
        float acc[KT];
        #pragma unroll
        for (int j = 0; j < KT; ++j) acc[j] = 0.0f;

        #pragma unroll 1
        for (int ch = 0; ch < 4; ++ch) {
            const int st = kt * 4 + ch;
            // issue next chunk into the other buffer. Its last reader was
            // stage st-1, protected by the previous barrier. The barrier
            // below (vmcnt(0) drain) lands ~8K cycles after this issue.
            if (st + 1 < NKT * 4) {
                const int nst = st + 1;
                stage_issue(eT, cbuf[nst & 1],
                            kb0 + (nst >> 2) * KT, (nst & 3) * DCH, t);
            }
            const float* cb = cbuf[st & 1];
            #pragma unroll 1
            for (int it2 = 0; it2 < 4; ++it2) {
                const int dg = ch * DCH + it2 * 16;   // d within kt (z index)
                const int rb = it2 * 16;              // row within chunk
                zpf(zp, dg + 8, zb);                  // prefetch d+8..d+15
                fma8(cb, rb, za, acc);                // compute d..d+7
                zpf(zp, dg + 16, za);                 // prefetch d+16..d+23
                fma8(cb, rb + 8, zb, acc);            // compute d+8..d+15
            }
            __syncthreads();
        }

        // epilogue: dist = (An - M2) + ee, k ascending -> first-min ties
        #pragma unroll
        for (int j = 0; j < KT; ++j) {
            const float dist = (An - acc[j]) + ee[kbase + j];
            if (dist < bestv) { bestv = dist; bestk = kbase + j; }
        }
    }

    // Order-preserving fp32 encode; lexicographic (dist, k) min across
    // splits. Equal dist bits -> lower k wins = first-min semantics.
    unsigned int vb = __float_as_uint(bestv);
    vb = (vb & 0x80000000u) ? ~vb : (vb | 0x80000000u);
    atomicMin(&packed[n], ((unsigned long long)vb << 32) | (unsigned int)bestk);
}

__global__ void unpack_kernel(const unsigned long long* __restrict__ packed,
                              int* __restrict__ out) {
    int n = blockIdx.x * blockDim.x + threadIdx.x;
    out[n] = (int)(packed[n] & 0xFFFFFFFFull);
}

extern "C" void kernel_launch(void* const* d_in, const int* in_sizes, int n_in,
                              void* d_out, int out_size, void* d_ws, size_t ws_size,
                              hipStream_t stream) {
    const float* z   = (const float*)d_in[0];   // [16,256,64,64]
    const float* emb = (const float*)d_in[1];   // [1024,256]
    int* out = (int*)d_out;                     // [65536] int32

    float* wsEE = (float*)d_ws;                     // 1024
    float* wsA  = wsEE + K_DIM;                     // 65536
    float* wsET = wsA + N_TOT;                      // 262144
    unsigned long long* wsPacked =
        (unsigned long long*)(wsET + (size_t)D_DIM * K_DIM);  // 65536 u64

    hipMemsetAsync(wsPacked, 0xFF, (size_t)N_TOT * sizeof(unsigned long long),
                   stream);
    et_kernel<<<dim3(K_DIM / 32, D_DIM / 32), dim3(32, 8), 0, stream>>>(emb, wsET);
    ee_kernel<<<K_DIM / 256, 256, 0, stream>>>(emb, wsEE);
    a_kernel<<<2 * N_TOT / 256, 256, 0, stream>>>(z, wsA);
    vq_partial<<<N_TOT / 256 * NSPLIT, 256, 0, stream>>>(z, wsET, wsA, wsEE,
                                                         wsPacked);
    unpack_kernel<<<N_TOT / 256, 256, 0, stream>>>(wsPacked, out);
}